// Round 1
// baseline (49.096 us; speedup 1.0000x reference)
//
#include <hip/hip_runtime.h>

// LDDMM variational evolve: N-body Gaussian kernel sums, N=8192, D=3, fp32.
// dmom_i = (1/SIG2) * sum_j K_ij * <mom_i,mom_j> * (pos_i - pos_j)
// dpos_i = sum_j K_ij * mom_j
// K_ij = exp(-||pos_i-pos_j||^2 / (2*SIG2)), SIG2 = 0.01 -> exp(-50*d2)

#define NPTS    8192
#define THREADS 256
#define ILANES  2              // i-points per thread
#define IBLK    (THREADS * ILANES)   // 512 i's per block
#define JBLK    256            // j's per block (== THREADS for easy staging)
#define NJC     (NPTS / JBLK)  // 32 j-chunks

template <bool ATOMIC>
__global__ __launch_bounds__(THREADS)
void lddmm_main(const float* __restrict__ mom,
                const float* __restrict__ pos,
                float* __restrict__ partial,   // [NJC][6][NPTS] when !ATOMIC
                float* __restrict__ out)       // used when ATOMIC
{
    __shared__ float4 sp[JBLK];
    __shared__ float4 sm[JBLK];

    const int t  = threadIdx.x;
    const int i0 = blockIdx.x * IBLK;
    const int jc = blockIdx.y;
    const int jbase = jc * JBLK;

    // Stage this block's j-chunk into LDS (coalesced: thread t loads point jbase+t).
    {
        const int j = jbase + t;
        sp[t] = make_float4(pos[3*j+0], pos[3*j+1], pos[3*j+2], 0.0f);
        sm[t] = make_float4(mom[3*j+0], mom[3*j+1], mom[3*j+2], 0.0f);
    }
    __syncthreads();

    const int iA = i0 + t;
    const int iB = i0 + THREADS + t;

    const float xA = pos[3*iA+0], yA = pos[3*iA+1], zA = pos[3*iA+2];
    const float pxA = mom[3*iA+0], pyA = mom[3*iA+1], pzA = mom[3*iA+2];
    const float xB = pos[3*iB+0], yB = pos[3*iB+1], zB = pos[3*iB+2];
    const float pxB = mom[3*iB+0], pyB = mom[3*iB+1], pzB = mom[3*iB+2];

    float amAx=0.f, amAy=0.f, amAz=0.f, apAx=0.f, apAy=0.f, apAz=0.f;
    float amBx=0.f, amBy=0.f, amBz=0.f, apBx=0.f, apBy=0.f, apBz=0.f;

    #pragma unroll 4
    for (int j = 0; j < JBLK; ++j) {
        const float4 P = sp[j];   // broadcast ds_read_b128
        const float4 M = sm[j];

        // i = A
        {
            const float dx = xA - P.x, dy = yA - P.y, dz = zA - P.z;
            const float d2 = dx*dx + dy*dy + dz*dz;
            const float K  = __expf(-50.0f * d2);
            const float C  = pxA*M.x + pyA*M.y + pzA*M.z;
            const float s  = K * C;
            amAx += s*dx;  amAy += s*dy;  amAz += s*dz;
            apAx += K*M.x; apAy += K*M.y; apAz += K*M.z;
        }
        // i = B
        {
            const float dx = xB - P.x, dy = yB - P.y, dz = zB - P.z;
            const float d2 = dx*dx + dy*dy + dz*dz;
            const float K  = __expf(-50.0f * d2);
            const float C  = pxB*M.x + pyB*M.y + pzB*M.z;
            const float s  = K * C;
            amBx += s*dx;  amBy += s*dy;  amBz += s*dz;
            apBx += K*M.x; apBy += K*M.y; apBz += K*M.z;
        }
    }

    const float INV_SIG2 = 100.0f;
    if (!ATOMIC) {
        // partial[jc][comp][i], comp 0..2 = dmom.xyz, 3..5 = dpos.xyz
        float* base = partial + (size_t)jc * (6 * NPTS);
        base[0*NPTS + iA] = amAx * INV_SIG2;
        base[1*NPTS + iA] = amAy * INV_SIG2;
        base[2*NPTS + iA] = amAz * INV_SIG2;
        base[3*NPTS + iA] = apAx;
        base[4*NPTS + iA] = apAy;
        base[5*NPTS + iA] = apAz;
        base[0*NPTS + iB] = amBx * INV_SIG2;
        base[1*NPTS + iB] = amBy * INV_SIG2;
        base[2*NPTS + iB] = amBz * INV_SIG2;
        base[3*NPTS + iB] = apBx;
        base[4*NPTS + iB] = apBy;
        base[5*NPTS + iB] = apBz;
    } else {
        atomicAdd(&out[3*iA+0], amAx * INV_SIG2);
        atomicAdd(&out[3*iA+1], amAy * INV_SIG2);
        atomicAdd(&out[3*iA+2], amAz * INV_SIG2);
        atomicAdd(&out[3*NPTS + 3*iA+0], apAx);
        atomicAdd(&out[3*NPTS + 3*iA+1], apAy);
        atomicAdd(&out[3*NPTS + 3*iA+2], apAz);
        atomicAdd(&out[3*iB+0], amBx * INV_SIG2);
        atomicAdd(&out[3*iB+1], amBy * INV_SIG2);
        atomicAdd(&out[3*iB+2], amBz * INV_SIG2);
        atomicAdd(&out[3*NPTS + 3*iB+0], apBx);
        atomicAdd(&out[3*NPTS + 3*iB+1], apBy);
        atomicAdd(&out[3*NPTS + 3*iB+2], apBz);
    }
}

__global__ __launch_bounds__(256)
void lddmm_reduce(const float* __restrict__ partial, float* __restrict__ out)
{
    const int idx = blockIdx.x * blockDim.x + threadIdx.x;  // 0 .. 6*NPTS-1
    int comp, i;
    if (idx < 3 * NPTS) { i = idx / 3; comp = idx % 3; }            // dmom
    else { const int r = idx - 3 * NPTS; i = r / 3; comp = 3 + r % 3; }  // dpos
    float s = 0.0f;
    #pragma unroll
    for (int jc = 0; jc < NJC; ++jc)
        s += partial[(size_t)jc * (6 * NPTS) + (size_t)comp * NPTS + i];
    out[idx] = s;
}

extern "C" void kernel_launch(void* const* d_in, const int* in_sizes, int n_in,
                              void* d_out, int out_size, void* d_ws, size_t ws_size,
                              hipStream_t stream)
{
    const float* mom = (const float*)d_in[0];
    const float* pos = (const float*)d_in[1];
    float* out = (float*)d_out;

    const size_t need = (size_t)NJC * 6 * NPTS * sizeof(float);  // 6.29 MB
    dim3 grid(NPTS / IBLK, NJC);

    if (ws_size >= need) {
        float* partial = (float*)d_ws;
        lddmm_main<false><<<grid, THREADS, 0, stream>>>(mom, pos, partial, out);
        lddmm_reduce<<<(6 * NPTS) / 256, 256, 0, stream>>>(partial, out);
    } else {
        hipMemsetAsync(out, 0, (size_t)6 * NPTS * sizeof(float), stream);
        lddmm_main<true><<<grid, THREADS, 0, stream>>>(mom, pos, nullptr, out);
    }
}